// Round 1
// baseline (576.582 us; speedup 1.0000x reference)
//
#include <hip/hip_runtime.h>
#include <stdint.h>

typedef unsigned short u16;
typedef __attribute__((ext_vector_type(8))) short short8;   // 8 bf16 (4 VGPRs) MFMA frag
typedef __attribute__((ext_vector_type(4))) float f32x4;    // MFMA C/D frag
typedef __attribute__((ext_vector_type(4))) float float4v;
typedef __attribute__((ext_vector_type(4))) u16 u16x4;

typedef const __attribute__((address_space(1))) void gvoid_t;
typedef __attribute__((address_space(3))) void lvoid_t;

#define N_EMBD 1024
#define NH 16
#define DH 64
#define TSEQ 2048
#define BATCH 4

#define MFMA16 __builtin_amdgcn_mfma_f32_16x16x32_bf16

__device__ __forceinline__ u16 f32_to_bf16(float f) {
  uint32_t x = __builtin_bit_cast(uint32_t, f);
  x = (x + 0x7FFFu + ((x >> 16) & 1u)) >> 16;   // round-to-nearest-even
  return (u16)x;
}

__device__ __forceinline__ void gload_lds16(const void* g, void* l) {
  __builtin_amdgcn_global_load_lds((gvoid_t*)g, (lvoid_t*)l, 16, 0, 0);
}

// ---------------- elementwise f32 -> bf16 ----------------
__global__ void cvt_kernel(const float* __restrict__ in, u16* __restrict__ out, int n4) {
  int i = blockIdx.x * blockDim.x + threadIdx.x;
  if (i < n4) {
    float4v v = *(const float4v*)(in + (size_t)i * 4);
    u16x4 o;
    o[0] = f32_to_bf16(v[0]); o[1] = f32_to_bf16(v[1]);
    o[2] = f32_to_bf16(v[2]); o[3] = f32_to_bf16(v[3]);
    *(u16x4*)(out + (size_t)i * 4) = o;
  }
}

// ---------------- tiled transpose (optionally f32->bf16) ----------------
__device__ __forceinline__ u16 cvt_elem(float v) { return f32_to_bf16(v); }
__device__ __forceinline__ u16 cvt_elem(u16 v) { return v; }

template <typename TIN>
__global__ void transpose_bf16(const TIN* __restrict__ in, u16* __restrict__ out,
                               int R, int C, long ibs, long obs) {
  __shared__ u16 tile[32][33];
  const TIN* ip = in + (size_t)blockIdx.z * ibs;
  u16* op = out + (size_t)blockIdx.z * obs;
  int r0 = blockIdx.x * 32, c0 = blockIdx.y * 32;
  int tx = threadIdx.x & 31, ty = threadIdx.x >> 5;   // 256 thr: ty 0..7
#pragma unroll
  for (int i = 0; i < 4; i++)
    tile[ty + i * 8][tx] = cvt_elem(ip[(size_t)(r0 + ty + i * 8) * C + c0 + tx]);
  __syncthreads();
#pragma unroll
  for (int i = 0; i < 4; i++)
    op[(size_t)(c0 + ty + i * 8) * R + r0 + tx] = tile[tx][ty + i * 8];
}

// ---------------- 128x128 GEMM, A[M][K] bf16, Bt[N][K] bf16 ----------------
// EPI==0: C f32 linear.  EPI==1: scatter to Q/K/V [B,H,T,D] bf16.
template <int EPI>
__global__ __launch_bounds__(256)
void gemm128(const u16* __restrict__ A, const u16* __restrict__ Bt,
             float* __restrict__ Cf, u16* __restrict__ Qb, u16* __restrict__ Kb,
             u16* __restrict__ Vb, int M, int N, int K) {
  __shared__ u16 sA[128 * 64];
  __shared__ u16 sB[128 * 64];
  const int tid = threadIdx.x;
  const int lane = tid & 63, w = tid >> 6;
  const int wm = w >> 1, wn = w & 1;
  const int l15 = lane & 15, lg = lane >> 4;
  const int m0 = blockIdx.x * 128, n0 = blockIdx.y * 128;
  f32x4 acc[4][4] = {};
  const int srow = tid >> 3, scb = tid & 7;

  auto stage = [&](int k0) {
#pragma unroll
    for (int i = 0; i < 4; i++) {
      int row = i * 32 + srow;
      int cb = scb ^ (row & 7);                      // pre-swizzled SOURCE (rule #21)
      gload_lds16(A + (size_t)(m0 + row) * K + k0 + cb * 8, sA + i * 2048 + w * 512);
      gload_lds16(Bt + (size_t)(n0 + row) * K + k0 + cb * 8, sB + i * 2048 + w * 512);
    }
  };

  stage(0);
  for (int k0 = 0; k0 < K; k0 += 64) {
    __syncthreads();                                  // staging for k0 visible
    short8 af[4][2], bf[4][2];
#pragma unroll
    for (int mi = 0; mi < 4; mi++)
#pragma unroll
      for (int kk = 0; kk < 2; kk++) {
        int ra = wm * 64 + mi * 16 + l15;
        af[mi][kk] = *(const short8*)(sA + ra * 64 + ((kk * 4 + lg) ^ (ra & 7)) * 8);
        int rb = wn * 64 + mi * 16 + l15;
        bf[mi][kk] = *(const short8*)(sB + rb * 64 + ((kk * 4 + lg) ^ (rb & 7)) * 8);
      }
    if (k0 + 64 < K) {
      __syncthreads();                                // all frag reads done
      stage(k0 + 64);                                 // prefetch overlaps MFMA
    }
#pragma unroll
    for (int kk = 0; kk < 2; kk++)
#pragma unroll
      for (int mi = 0; mi < 4; mi++)
#pragma unroll
        for (int ni = 0; ni < 4; ni++)
          acc[mi][ni] = MFMA16(af[mi][kk], bf[ni][kk], acc[mi][ni], 0, 0, 0);
  }

#pragma unroll
  for (int mi = 0; mi < 4; mi++)
#pragma unroll
    for (int ni = 0; ni < 4; ni++)
#pragma unroll
      for (int r = 0; r < 4; r++) {
        int m = m0 + wm * 64 + mi * 16 + lg * 4 + r;  // C row = (lane>>4)*4+reg
        int n = n0 + wn * 64 + ni * 16 + l15;         // C col = lane&15
        float v = acc[mi][ni][r];
        if (EPI == 0) {
          Cf[(size_t)m * N + n] = v;
        } else {
          int b = m >> 11, t = m & 2047;
          int sec = n >> 10, c = n & 1023;
          int h = c >> 6, d = c & 63;
          u16* dst = (sec == 0) ? Qb : ((sec == 1) ? Kb : Vb);
          dst[(((size_t)(b * NH + h)) * TSEQ + t) * DH + d] = f32_to_bf16(v);
        }
      }
}

// ---------------- causal flash attention ----------------
// grid (T/256, B*H); 4 waves, wave w owns 64 q-rows. K in [B,H,T,D], V^T in [B,H,D,T].
__global__ __launch_bounds__(256)
void attn_kernel(const u16* __restrict__ Q, const u16* __restrict__ K,
                 const u16* __restrict__ Vt, u16* __restrict__ AO) {
  __shared__ u16 sK[64 * 64];
  __shared__ u16 sV[64 * 64];
  __shared__ u16 sP[4][64 * 64];
  const int tid = threadIdx.x;
  const int lane = tid & 63, w = tid >> 6;
  const int l15 = lane & 15, lg = lane >> 4;
  const int bh = blockIdx.y;
  const int qw0 = blockIdx.x * 256 + w * 64;
  const size_t bh_off = (size_t)bh * TSEQ * DH;

  short8 aq[4][2];
#pragma unroll
  for (int mi = 0; mi < 4; mi++)
#pragma unroll
    for (int kk = 0; kk < 2; kk++)
      aq[mi][kk] = *(const short8*)(Q + bh_off + (size_t)(qw0 + mi * 16 + l15) * DH + kk * 32 + lg * 8);

  f32x4 accO[4][4] = {};
  float mrow[4][4], lrow[4][4];
#pragma unroll
  for (int mi = 0; mi < 4; mi++)
#pragma unroll
    for (int r = 0; r < 4; r++) { mrow[mi][r] = -3e38f; lrow[mi][r] = 0.f; }

  const float SC = 0.125f * 1.44269504088896340736f;  // 1/sqrt(64) * log2(e)
  const int ntiles = blockIdx.x * 4 + 4;
  const int srow = tid >> 3, scb = tid & 7;

  for (int it = 0; it < ntiles; it++) {
    const int k0 = it * 64;
    __syncthreads();                                  // prior compute done
#pragma unroll
    for (int i = 0; i < 2; i++) {
      int row = i * 32 + srow;
      int cb = scb ^ (row & 7);
      gload_lds16(K + bh_off + (size_t)(k0 + row) * DH + cb * 8, sK + i * 2048 + w * 512);
      gload_lds16(Vt + bh_off + (size_t)row * TSEQ + k0 + cb * 8, sV + i * 2048 + w * 512);
    }
    __syncthreads();                                  // staging visible
    if (k0 > qw0) continue;                           // causal: this wave done

    f32x4 accS[4][4] = {};
    short8 bk[4][2];
#pragma unroll
    for (int ni = 0; ni < 4; ni++)
#pragma unroll
      for (int kk = 0; kk < 2; kk++) {
        int rb = ni * 16 + l15;
        bk[ni][kk] = *(const short8*)(sK + rb * 64 + ((kk * 4 + lg) ^ (rb & 7)) * 8);
      }
#pragma unroll
    for (int kk = 0; kk < 2; kk++)
#pragma unroll
      for (int mi = 0; mi < 4; mi++)
#pragma unroll
        for (int ni = 0; ni < 4; ni++)
          accS[mi][ni] = MFMA16(aq[mi][kk], bk[ni][kk], accS[mi][ni], 0, 0, 0);

    const bool diag = (k0 == qw0);
#pragma unroll
    for (int mi = 0; mi < 4; mi++)
#pragma unroll
      for (int ni = 0; ni < 4; ni++)
#pragma unroll
        for (int r = 0; r < 4; r++) {
          float s = accS[mi][ni][r] * SC;
          if (diag && (ni * 16 + l15 > mi * 16 + lg * 4 + r)) s = -1e30f;
          accS[mi][ni][r] = s;
        }

    u16* sPw = sP[w];
#pragma unroll
    for (int mi = 0; mi < 4; mi++)
#pragma unroll
      for (int r = 0; r < 4; r++) {
        float v = fmaxf(fmaxf(accS[mi][0][r], accS[mi][1][r]),
                        fmaxf(accS[mi][2][r], accS[mi][3][r]));
        v = fmaxf(v, __shfl_xor(v, 1));
        v = fmaxf(v, __shfl_xor(v, 2));
        v = fmaxf(v, __shfl_xor(v, 4));
        v = fmaxf(v, __shfl_xor(v, 8));
        float mold = mrow[mi][r];
        float mnew = fmaxf(mold, v);
        float alpha = exp2f(mold - mnew);
        mrow[mi][r] = mnew;
        float rsum = 0.f;
        int prow = mi * 16 + lg * 4 + r;
#pragma unroll
        for (int ni = 0; ni < 4; ni++) {
          float p = exp2f(accS[mi][ni][r] - mnew);
          rsum += p;
          int col = ni * 16 + l15;
          sPw[prow * 64 + (((col >> 3) ^ (prow & 7)) << 3) + (col & 7)] = f32_to_bf16(p);
        }
        rsum += __shfl_xor(rsum, 1);
        rsum += __shfl_xor(rsum, 2);
        rsum += __shfl_xor(rsum, 4);
        rsum += __shfl_xor(rsum, 8);
        lrow[mi][r] = lrow[mi][r] * alpha + rsum;
#pragma unroll
        for (int di = 0; di < 4; di++) accO[mi][di][r] *= alpha;
      }

    asm volatile("s_waitcnt lgkmcnt(0)" ::: "memory"); // P writes visible to own wave

    short8 bv[2][4];
#pragma unroll
    for (int kk = 0; kk < 2; kk++)
#pragma unroll
      for (int di = 0; di < 4; di++) {
        int rv = di * 16 + l15;
        bv[kk][di] = *(const short8*)(sV + rv * 64 + ((kk * 4 + lg) ^ (rv & 7)) * 8);
      }
#pragma unroll
    for (int mi = 0; mi < 4; mi++) {
      short8 ap[2];
#pragma unroll
      for (int kk = 0; kk < 2; kk++) {
        int rp = mi * 16 + l15;
        ap[kk] = *(const short8*)(sPw + rp * 64 + ((kk * 4 + lg) ^ (rp & 7)) * 8);
      }
#pragma unroll
      for (int kk = 0; kk < 2; kk++)
#pragma unroll
        for (int di = 0; di < 4; di++)
          accO[mi][di] = MFMA16(ap[kk], bv[kk][di], accO[mi][di], 0, 0, 0);
    }
  }

  const int b = bh >> 4, h = bh & 15;
#pragma unroll
  for (int mi = 0; mi < 4; mi++)
#pragma unroll
    for (int r = 0; r < 4; r++) {
      float inv = 1.0f / lrow[mi][r];
      int t = qw0 + mi * 16 + lg * 4 + r;
#pragma unroll
      for (int di = 0; di < 4; di++) {
        int c = h * 64 + di * 16 + l15;
        AO[((size_t)b * TSEQ + t) * N_EMBD + c] = f32_to_bf16(accO[mi][di][r] * inv);
      }
    }
}

extern "C" void kernel_launch(void* const* d_in, const int* in_sizes, int n_in,
                              void* d_out, int out_size, void* d_ws, size_t ws_size,
                              hipStream_t stream) {
  const float* x = (const float*)d_in[0];
  const float* w_qkv = (const float*)d_in[1];
  const float* w_out = (const float*)d_in[2];
  float* out = (float*)d_out;
  char* ws = (char*)d_ws;
  const size_t MB = 1 << 20;
  u16* xb    = (u16*)(ws);             // 16MB, reused as AO after gemm1
  u16* wqkvT = (u16*)(ws + 16 * MB);   // 6MB
  u16* woutT = (u16*)(ws + 22 * MB);   // 2MB
  u16* Qb    = (u16*)(ws + 24 * MB);   // 16MB
  u16* Kb    = (u16*)(ws + 40 * MB);   // 16MB
  u16* Vb    = (u16*)(ws + 56 * MB);   // 16MB
  u16* Vt    = (u16*)(ws + 72 * MB);   // 16MB  (total 88MB)
  u16* AO    = xb;

  cvt_kernel<<<8192, 256, 0, stream>>>(x, xb, (BATCH * TSEQ * N_EMBD) / 4);
  transpose_bf16<float><<<dim3(32, 96, 1), 256, 0, stream>>>(w_qkv, wqkvT, 1024, 3072, 0, 0);
  transpose_bf16<float><<<dim3(32, 32, 1), 256, 0, stream>>>(w_out, woutT, 1024, 1024, 0, 0);
  gemm128<1><<<dim3(64, 24), 256, 0, stream>>>(xb, wqkvT, nullptr, Qb, Kb, Vb,
                                               BATCH * TSEQ, 3 * N_EMBD, N_EMBD);
  transpose_bf16<u16><<<dim3(64, 2, 64), 256, 0, stream>>>(Vb, Vt, TSEQ, DH,
                                                           (long)TSEQ * DH, (long)TSEQ * DH);
  attn_kernel<<<dim3(TSEQ / 256, BATCH * NH), 256, 0, stream>>>(Qb, Kb, Vt, AO);
  gemm128<0><<<dim3(64, 8), 256, 0, stream>>>(AO, woutT, out, nullptr, nullptr, nullptr,
                                              BATCH * TSEQ, N_EMBD, N_EMBD);
}

// Round 4
// 287.723 us; speedup vs baseline: 2.0039x; 2.0039x over previous
//
#include <hip/hip_runtime.h>
#include <stdint.h>

typedef unsigned short u16;
typedef __attribute__((ext_vector_type(8))) short short8;   // 8 bf16 (4 VGPRs) MFMA frag
typedef __attribute__((ext_vector_type(4))) float f32x4;    // MFMA C/D frag
typedef __attribute__((ext_vector_type(4))) float float4v;
typedef __attribute__((ext_vector_type(4))) u16 u16x4;
typedef __attribute__((ext_vector_type(2))) uint32_t u32x2;

typedef const __attribute__((address_space(1))) void gvoid_t;
typedef __attribute__((address_space(3))) void lvoid_t;

#define N_EMBD 1024
#define NH 16
#define DH 64
#define TSEQ 2048
#define BATCH 4

#define MFMA16 __builtin_amdgcn_mfma_f32_16x16x32_bf16

__device__ __forceinline__ u16 f32_to_bf16(float f) {
  uint32_t x = __builtin_bit_cast(uint32_t, f);
  x = (x + 0x7FFFu + ((x >> 16) & 1u)) >> 16;   // round-to-nearest-even
  return (u16)x;
}

__device__ __forceinline__ uint32_t pk_bf16(float a, float b) {
  return (uint32_t)f32_to_bf16(a) | ((uint32_t)f32_to_bf16(b) << 16);
}

__device__ __forceinline__ void gload_lds16(const void* g, void* l) {
  __builtin_amdgcn_global_load_lds((gvoid_t*)g, (lvoid_t*)l, 16, 0, 0);
}

// ---------------- elementwise f32 -> bf16 ----------------
__global__ void cvt_kernel(const float* __restrict__ in, u16* __restrict__ out, int n4) {
  int i = blockIdx.x * blockDim.x + threadIdx.x;
  if (i < n4) {
    float4v v = *(const float4v*)(in + (size_t)i * 4);
    u16x4 o;
    o[0] = f32_to_bf16(v[0]); o[1] = f32_to_bf16(v[1]);
    o[2] = f32_to_bf16(v[2]); o[3] = f32_to_bf16(v[3]);
    *(u16x4*)(out + (size_t)i * 4) = o;
  }
}

// ---------------- tiled transpose (optionally f32->bf16) ----------------
__device__ __forceinline__ u16 cvt_elem(float v) { return f32_to_bf16(v); }
__device__ __forceinline__ u16 cvt_elem(u16 v) { return v; }

template <typename TIN>
__global__ void transpose_bf16(const TIN* __restrict__ in, u16* __restrict__ out,
                               int R, int C, long ibs, long obs) {
  __shared__ u16 tile[32][33];
  const TIN* ip = in + (size_t)blockIdx.z * ibs;
  u16* op = out + (size_t)blockIdx.z * obs;
  int r0 = blockIdx.x * 32, c0 = blockIdx.y * 32;
  int tx = threadIdx.x & 31, ty = threadIdx.x >> 5;   // 256 thr: ty 0..7
#pragma unroll
  for (int i = 0; i < 4; i++)
    tile[ty + i * 8][tx] = cvt_elem(ip[(size_t)(r0 + ty + i * 8) * C + c0 + tx]);
  __syncthreads();
#pragma unroll
  for (int i = 0; i < 4; i++)
    op[(size_t)(c0 + ty + i * 8) * R + r0 + tx] = tile[tx][ty + i * 8];
}

// ---------------- 128x128 GEMM, A[M][K] bf16, Bt[N][K] bf16 ----------------
// EPI==0: C f32 linear.  EPI==1: scatter to Q/K/V [B,H,T,D] bf16 (Q pre-scaled).
template <int EPI>
__global__ __launch_bounds__(256)
void gemm128(const u16* __restrict__ A, const u16* __restrict__ Bt,
             float* __restrict__ Cf, u16* __restrict__ Qb, u16* __restrict__ Kb,
             u16* __restrict__ Vb, int M, int N, int K) {
  __shared__ u16 sA[128 * 64];
  __shared__ u16 sB[128 * 64];
  const int tid = threadIdx.x;
  const int lane = tid & 63, w = tid >> 6;
  const int wm = w >> 1, wn = w & 1;
  const int l15 = lane & 15, lg = lane >> 4;
  const int m0 = blockIdx.x * 128, n0 = blockIdx.y * 128;
  f32x4 acc[4][4] = {};
  const int srow = tid >> 3, scb = tid & 7;

  auto stage = [&](int k0) {
#pragma unroll
    for (int i = 0; i < 4; i++) {
      int row = i * 32 + srow;
      int cb = scb ^ (row & 7);                      // pre-swizzled SOURCE (rule #21)
      gload_lds16(A + (size_t)(m0 + row) * K + k0 + cb * 8, sA + i * 2048 + w * 512);
      gload_lds16(Bt + (size_t)(n0 + row) * K + k0 + cb * 8, sB + i * 2048 + w * 512);
    }
  };

  stage(0);
  for (int k0 = 0; k0 < K; k0 += 64) {
    __syncthreads();                                  // staging for k0 visible
    short8 af[4][2], bf[4][2];
#pragma unroll
    for (int mi = 0; mi < 4; mi++)
#pragma unroll
      for (int kk = 0; kk < 2; kk++) {
        int ra = wm * 64 + mi * 16 + l15;
        af[mi][kk] = *(const short8*)(sA + ra * 64 + ((kk * 4 + lg) ^ (ra & 7)) * 8);
        int rb = wn * 64 + mi * 16 + l15;
        bf[mi][kk] = *(const short8*)(sB + rb * 64 + ((kk * 4 + lg) ^ (rb & 7)) * 8);
      }
    if (k0 + 64 < K) {
      __syncthreads();                                // all frag reads done
      stage(k0 + 64);                                 // prefetch overlaps MFMA
    }
#pragma unroll
    for (int kk = 0; kk < 2; kk++)
#pragma unroll
      for (int mi = 0; mi < 4; mi++)
#pragma unroll
        for (int ni = 0; ni < 4; ni++)
          acc[mi][ni] = MFMA16(af[mi][kk], bf[ni][kk], acc[mi][ni], 0, 0, 0);
  }

#pragma unroll
  for (int mi = 0; mi < 4; mi++)
#pragma unroll
    for (int ni = 0; ni < 4; ni++)
#pragma unroll
      for (int r = 0; r < 4; r++) {
        int m = m0 + wm * 64 + mi * 16 + lg * 4 + r;  // C row = (lane>>4)*4+reg
        int n = n0 + wn * 64 + ni * 16 + l15;         // C col = lane&15
        float v = acc[mi][ni][r];
        if (EPI == 0) {
          Cf[(size_t)m * N + n] = v;
        } else {
          int b = m >> 11, t = m & 2047;
          int sec = n >> 10, c = n & 1023;
          int h = c >> 6, d = c & 63;
          if (sec == 0) v *= 0.1803368801111204f;     // 1/sqrt(64) * log2(e) folded into Q
          u16* dst = (sec == 0) ? Qb : ((sec == 1) ? Kb : Vb);
          dst[(((size_t)(b * NH + h)) * TSEQ + t) * DH + d] = f32_to_bf16(v);
        }
      }
}

// ---------------- causal flash attention, swapped-QK in-register softmax ----
// 1D grid of 1024 blocks (longest-first): qt = 15 - id/64, bh = id & 63.
// Block owns 128 q-rows; wave w owns 16-q groups {qb0+w*16, qb0+64+w*16}.
// S^T = mfma(K,Q): lane holds S[k=kb*16+lg*4+r][q=q0+l15] -> stats at l15=q.
// O^T = mfma(V^T,P): lane holds O[d=db*16+lg*4+r][q=q0+l15] -> rescale per-lane.
__global__ __launch_bounds__(256)
void attn_kernel(const u16* __restrict__ Q, const u16* __restrict__ K,
                 const u16* __restrict__ Vt, u16* __restrict__ AO) {
  __shared__ u16 sK[2][64 * 64];
  __shared__ u16 sV[2][64 * 64];
  __shared__ u16 sP[4][32 * 64];
  const int tid = threadIdx.x;
  const int lane = tid & 63, w = tid >> 6;
  const int l15 = lane & 15, lg = lane >> 4;
  const int id = blockIdx.x;
  const int qt = 15 - (id >> 6);
  const int bh = id & 63;
  const int qb0 = qt * 128;
  const size_t bh_off = (size_t)bh * TSEQ * DH;
  const int q0a = qb0 + w * 16;          // qg=0 16-q group
  const int q0b = qb0 + 64 + w * 16;     // qg=1 16-q group

  // Q B-fragments, loaded once (Q pre-scaled by 0.125*log2e in gemm1)
  short8 bq[2][2];
#pragma unroll
  for (int qg = 0; qg < 2; qg++) {
    int q0 = qg ? q0b : q0a;
#pragma unroll
    for (int kk = 0; kk < 2; kk++)
      bq[qg][kk] = *(const short8*)(Q + bh_off + (size_t)(q0 + l15) * DH + kk * 32 + lg * 8);
  }

  f32x4 accO[2][4] = {};                 // accO[qg][db]: O^T fragment
  float mrow[2] = {-3e38f, -3e38f};
  float lrow[2] = {0.f, 0.f};

  const int srow = tid >> 3, scb = tid & 7;
  u16* sPw = sP[w];

  auto stage = [&](int it, int buf) {
    const int k0 = it * 64;
    u16* dK = sK[buf];
    u16* dV = sV[buf];
#pragma unroll
    for (int i = 0; i < 2; i++) {
      int r = i * 32 + srow;
      int cb = scb ^ (r & 7);
      gload_lds16(K + bh_off + (size_t)(k0 + r) * DH + cb * 8, dK + i * 2048 + w * 512);
      gload_lds16(Vt + bh_off + (size_t)r * TSEQ + k0 + cb * 8, dV + i * 2048 + w * 512);
    }
  };

  const int ntiles = 2 * qt + 2;
  stage(0, 0);
  for (int it = 0; it < ntiles; ++it) {
    const int k0 = it * 64;
    __syncthreads();                       // stage(it) visible; prev-tile reads done
    const int cur = it & 1;
    if (it + 1 < ntiles) stage(it + 1, cur ^ 1);   // prefetch overlaps this tile
    if (k0 > q0b + 15) continue;           // wave fully done (causal); barriers still met

    const u16* cK = sK[cur];
    const u16* cV = sV[cur];

    // K A-fragments
    short8 ak[4][2];
#pragma unroll
    for (int kb = 0; kb < 4; kb++)
#pragma unroll
      for (int kk = 0; kk < 2; kk++) {
        int rk = kb * 16 + l15;
        ak[kb][kk] = *(const short8*)(cK + rk * 64 + (((kk * 4 + lg) ^ (rk & 7)) * 8));
      }

#pragma unroll
    for (int qg = 0; qg < 2; qg++) {
      const int q0 = qg ? q0b : q0a;
      if (k0 <= q0 + 15) {                 // this 16-q group active for this tile
        // S^T = K·Q : lane holds S[k = kb*16+lg*4+r][q = q0+l15]
        f32x4 accST[4] = {};
#pragma unroll
        for (int kk = 0; kk < 2; kk++)
#pragma unroll
          for (int kb = 0; kb < 4; kb++)
            accST[kb] = MFMA16(ak[kb][kk], bq[qg][kk], accST[kb], 0, 0, 0);

        if (k0 + 63 > q0) {                // causal mask needed on this tile
#pragma unroll
          for (int kb = 0; kb < 4; kb++)
#pragma unroll
            for (int r = 0; r < 4; r++)
              if (k0 + kb * 16 + lg * 4 + r > q0 + l15) accST[kb][r] = -1e30f;
        }

        // in-register row softmax: 15 fmax + 2 shfl, exp2, 15 add + 2 shfl
        float mt = fmaxf(fmaxf(accST[0][0], accST[0][1]), fmaxf(accST[0][2], accST[0][3]));
#pragma unroll
        for (int kb = 1; kb < 4; kb++)
          mt = fmaxf(mt, fmaxf(fmaxf(accST[kb][0], accST[kb][1]),
                               fmaxf(accST[kb][2], accST[kb][3])));
        mt = fmaxf(mt, __shfl_xor(mt, 16));
        mt = fmaxf(mt, __shfl_xor(mt, 32));
        const float mold = mrow[qg];
        const float mnew = fmaxf(mold, mt);
        const float alpha = exp2f(mold - mnew);
        mrow[qg] = mnew;

        const int prow = qg * 16 + l15;
        float rsum = 0.f;
#pragma unroll
        for (int kb = 0; kb < 4; kb++) {
          float p0 = exp2f(accST[kb][0] - mnew);
          float p1 = exp2f(accST[kb][1] - mnew);
          float p2 = exp2f(accST[kb][2] - mnew);
          float p3 = exp2f(accST[kb][3] - mnew);
          rsum += (p0 + p1) + (p2 + p3);
          // P[q][k]: k = kb*16+lg*4+{0..3} consecutive -> one 8B swizzled write
          int off32 = prow * 32 + ((((kb * 2 + (lg >> 1)) ^ (prow & 7)) << 2) | ((lg & 1) << 1));
          uint32_t* dst = (uint32_t*)sPw + off32;
          dst[0] = pk_bf16(p0, p1);
          dst[1] = pk_bf16(p2, p3);
        }
        rsum += __shfl_xor(rsum, 16);
        rsum += __shfl_xor(rsum, 32);
        lrow[qg] = lrow[qg] * alpha + rsum;
        // O^T rescale: accO col = q = l15 -> alpha is per-lane correct
#pragma unroll
        for (int di = 0; di < 4; di++)
#pragma unroll
          for (int j = 0; j < 4; j++) accO[qg][di][j] *= alpha;
      }
    }

    asm volatile("s_waitcnt lgkmcnt(0)" ::: "memory");   // P visible to own wave

    // V^T fragments (used as MFMA *A* operand: rows = d)
    short8 bv[2][4];
#pragma unroll
    for (int kk = 0; kk < 2; kk++)
#pragma unroll
      for (int di = 0; di < 4; di++) {
        int rv = di * 16 + l15;
        bv[kk][di] = *(const short8*)(cV + rv * 64 + (((kk * 4 + lg) ^ (rv & 7)) * 8));
      }
#pragma unroll
    for (int qg = 0; qg < 2; qg++) {
      const int q0 = qg ? q0b : q0a;
      if (k0 <= q0 + 15) {
        const int prow = qg * 16 + l15;
        short8 ap[2];
#pragma unroll
        for (int kk = 0; kk < 2; kk++)
          ap[kk] = *(const short8*)(sPw + prow * 64 + (((kk * 4 + lg) ^ (prow & 7)) * 8));
        // O^T = V^T · P : D[d=db*16+lg*4+r][q=q0+l15]
#pragma unroll
        for (int kk = 0; kk < 2; kk++)
#pragma unroll
          for (int db = 0; db < 4; db++)
            accO[qg][db] = MFMA16(bv[kk][db], ap[kk], accO[qg][db], 0, 0, 0);
      }
    }
  }

  // epilogue: O^T frag -> lane writes q = q0+l15, d = db*16 + lg*4 + {0..3}
  const int b = bh >> 4, h = bh & 15;
#pragma unroll
  for (int qg = 0; qg < 2; qg++) {
    const int q0 = qg ? q0b : q0a;
    const int t = q0 + l15;
    const float inv = 1.0f / lrow[qg];
    u16* orow = AO + ((size_t)b * TSEQ + t) * N_EMBD + h * 64 + lg * 4;
#pragma unroll
    for (int db = 0; db < 4; db++) {
      u32x2 pkd;
      pkd[0] = pk_bf16(accO[qg][db][0] * inv, accO[qg][db][1] * inv);
      pkd[1] = pk_bf16(accO[qg][db][2] * inv, accO[qg][db][3] * inv);
      *(u32x2*)(orow + db * 16) = pkd;
    }
  }
}

extern "C" void kernel_launch(void* const* d_in, const int* in_sizes, int n_in,
                              void* d_out, int out_size, void* d_ws, size_t ws_size,
                              hipStream_t stream) {
  const float* x = (const float*)d_in[0];
  const float* w_qkv = (const float*)d_in[1];
  const float* w_out = (const float*)d_in[2];
  float* out = (float*)d_out;
  char* ws = (char*)d_ws;
  const size_t MB = 1 << 20;
  u16* xb    = (u16*)(ws);             // 16MB, reused as AO after gemm1
  u16* wqkvT = (u16*)(ws + 16 * MB);   // 6MB
  u16* woutT = (u16*)(ws + 22 * MB);   // 2MB
  u16* Qb    = (u16*)(ws + 24 * MB);   // 16MB
  u16* Kb    = (u16*)(ws + 40 * MB);   // 16MB
  u16* Vb    = (u16*)(ws + 56 * MB);   // 16MB
  u16* Vt    = (u16*)(ws + 72 * MB);   // 16MB  (total 88MB)
  u16* AO    = xb;

  cvt_kernel<<<8192, 256, 0, stream>>>(x, xb, (BATCH * TSEQ * N_EMBD) / 4);
  transpose_bf16<float><<<dim3(32, 96, 1), 256, 0, stream>>>(w_qkv, wqkvT, 1024, 3072, 0, 0);
  transpose_bf16<float><<<dim3(32, 32, 1), 256, 0, stream>>>(w_out, woutT, 1024, 1024, 0, 0);
  gemm128<1><<<dim3(64, 24), 256, 0, stream>>>(xb, wqkvT, nullptr, Qb, Kb, Vb,
                                               BATCH * TSEQ, 3 * N_EMBD, N_EMBD);
  transpose_bf16<u16><<<dim3(64, 2, 64), 256, 0, stream>>>(Vb, Vt, TSEQ, DH,
                                                           (long)TSEQ * DH, (long)TSEQ * DH);
  attn_kernel<<<1024, 256, 0, stream>>>(Qb, Kb, Vt, AO);
  gemm128<0><<<dim3(64, 8), 256, 0, stream>>>(AO, woutT, out, nullptr, nullptr, nullptr,
                                              BATCH * TSEQ, N_EMBD, N_EMBD);
}

// Round 5
// 238.228 us; speedup vs baseline: 2.4203x; 1.2078x over previous
//
#include <hip/hip_runtime.h>
#include <stdint.h>

typedef unsigned short u16;
typedef __attribute__((ext_vector_type(8))) short short8;   // 8 bf16 (4 VGPRs) MFMA frag
typedef __attribute__((ext_vector_type(4))) float f32x4;    // MFMA C/D frag
typedef __attribute__((ext_vector_type(4))) float float4v;
typedef __attribute__((ext_vector_type(2))) uint32_t u32x2;

typedef const __attribute__((address_space(1))) void gvoid_t;
typedef __attribute__((address_space(3))) void lvoid_t;

#define N_EMBD 1024
#define NH 16
#define DH 64
#define TSEQ 2048
#define BATCH 4

#define MFMA16 __builtin_amdgcn_mfma_f32_16x16x32_bf16

__device__ __forceinline__ u16 f32_to_bf16(float f) {
  uint32_t x = __builtin_bit_cast(uint32_t, f);
  x = (x + 0x7FFFu + ((x >> 16) & 1u)) >> 16;   // round-to-nearest-even
  return (u16)x;
}

// HW packed f32x2 -> bf16x2 (RNE). No builtin on gfx950 -> inline asm (m240).
__device__ __forceinline__ uint32_t cvtpk(float lo, float hi) {
  uint32_t r;
  asm("v_cvt_pk_bf16_f32 %0, %1, %2" : "=v"(r) : "v"(lo), "v"(hi));
  return r;
}

__device__ __forceinline__ float exp2v(float x) { return __builtin_amdgcn_exp2f(x); }

__device__ __forceinline__ void gload_lds16(const void* g, void* l) {
  __builtin_amdgcn_global_load_lds((gvoid_t*)g, (lvoid_t*)l, 16, 0, 0);
}

// ---------------- elementwise f32 -> bf16 ----------------
__global__ void cvt_kernel(const float* __restrict__ in, u16* __restrict__ out, int n4) {
  int i = blockIdx.x * blockDim.x + threadIdx.x;
  if (i < n4) {
    float4v v = *(const float4v*)(in + (size_t)i * 4);
    u32x2 o;
    o[0] = cvtpk(v[0], v[1]);
    o[1] = cvtpk(v[2], v[3]);
    *(u32x2*)(out + (size_t)i * 4) = o;
  }
}

// ---------------- tiled transpose f32->bf16 (weights only) ----------------
__global__ void transpose_bf16(const float* __restrict__ in, u16* __restrict__ out,
                               int R, int C) {
  __shared__ u16 tile[32][33];
  int r0 = blockIdx.x * 32, c0 = blockIdx.y * 32;
  int tx = threadIdx.x & 31, ty = threadIdx.x >> 5;   // 256 thr: ty 0..7
#pragma unroll
  for (int i = 0; i < 4; i++)
    tile[ty + i * 8][tx] = f32_to_bf16(in[(size_t)(r0 + ty + i * 8) * C + c0 + tx]);
  __syncthreads();
#pragma unroll
  for (int i = 0; i < 4; i++)
    out[(size_t)(c0 + ty + i * 8) * R + r0 + tx] = tile[tx][ty + i * 8];
}

// ---------------- 128x128 GEMM, A[M][K] bf16, Bt[N][K] bf16 ----------------
// EPI==0: C f32 linear.
// EPI==1: scatter Q,K to [B,H,T,D] bf16 (Q pre-scaled); V direct to V^T [B,H,D,T].
template <int EPI>
__global__ __launch_bounds__(256)
void gemm128(const u16* __restrict__ A, const u16* __restrict__ Bt,
             float* __restrict__ Cf, u16* __restrict__ Qb, u16* __restrict__ Kb,
             u16* __restrict__ Vt, int M, int N, int K) {
  __shared__ u16 sA[128 * 64];
  __shared__ u16 sB[128 * 64];
  const int tid = threadIdx.x;
  const int lane = tid & 63, w = tid >> 6;
  const int wm = w >> 1, wn = w & 1;
  const int l15 = lane & 15, lg = lane >> 4;
  const int m0 = blockIdx.x * 128, n0 = blockIdx.y * 128;
  f32x4 acc[4][4] = {};
  const int srow = tid >> 3, scb = tid & 7;

  auto stage = [&](int k0) {
#pragma unroll
    for (int i = 0; i < 4; i++) {
      int row = i * 32 + srow;
      int cb = scb ^ (row & 7);                      // pre-swizzled SOURCE (rule #21)
      gload_lds16(A + (size_t)(m0 + row) * K + k0 + cb * 8, sA + i * 2048 + w * 512);
      gload_lds16(Bt + (size_t)(n0 + row) * K + k0 + cb * 8, sB + i * 2048 + w * 512);
    }
  };

  stage(0);
  for (int k0 = 0; k0 < K; k0 += 64) {
    __syncthreads();                                  // staging for k0 visible
    short8 af[4][2], bf[4][2];
#pragma unroll
    for (int mi = 0; mi < 4; mi++)
#pragma unroll
      for (int kk = 0; kk < 2; kk++) {
        int ra = wm * 64 + mi * 16 + l15;
        af[mi][kk] = *(const short8*)(sA + ra * 64 + ((kk * 4 + lg) ^ (ra & 7)) * 8);
        int rb = wn * 64 + mi * 16 + l15;
        bf[mi][kk] = *(const short8*)(sB + rb * 64 + ((kk * 4 + lg) ^ (rb & 7)) * 8);
      }
    if (k0 + 64 < K) {
      __syncthreads();                                // all frag reads done
      stage(k0 + 64);                                 // prefetch overlaps MFMA
    }
#pragma unroll
    for (int kk = 0; kk < 2; kk++)
#pragma unroll
      for (int mi = 0; mi < 4; mi++)
#pragma unroll
        for (int ni = 0; ni < 4; ni++)
          acc[mi][ni] = MFMA16(af[mi][kk], bf[ni][kk], acc[mi][ni], 0, 0, 0);
  }

#pragma unroll
  for (int mi = 0; mi < 4; mi++)
#pragma unroll
    for (int ni = 0; ni < 4; ni++) {
      const int mb = m0 + wm * 64 + mi * 16 + lg * 4;   // rows mb..mb+3 (t 4-aligned)
      const int n = n0 + wn * 64 + ni * 16 + l15;       // C col = lane&15
      if (EPI == 0) {
#pragma unroll
        for (int r = 0; r < 4; r++)
          Cf[(size_t)(mb + r) * N + n] = acc[mi][ni][r];
      } else {
        const int b = mb >> 11, t = mb & 2047;
        const int sec = n >> 10, c = n & 1023;          // sec uniform across wave
        const int h = c >> 6, d = c & 63;
        if (sec == 2) {
          // V^T [B,H,D,T]: 4 consecutive t per lane -> one 8B packed store
          u32x2 pkd;
          pkd[0] = cvtpk(acc[mi][ni][0], acc[mi][ni][1]);
          pkd[1] = cvtpk(acc[mi][ni][2], acc[mi][ni][3]);
          *(u32x2*)(Vt + ((size_t)(b * NH + h) * DH + d) * TSEQ + t) = pkd;
        } else {
          u16* dst = (sec == 0) ? Qb : Kb;
          const float sc = (sec == 0) ? 0.1803368801111204f : 1.0f;  // 1/8 * log2e
#pragma unroll
          for (int r = 0; r < 4; r++)
            dst[((size_t)(b * NH + h) * TSEQ + t + r) * DH + d] = f32_to_bf16(acc[mi][ni][r] * sc);
        }
      }
    }
}

// ---------------- causal flash attention, swapped-QK in-register softmax ----
// 1D grid of 1024 blocks (longest-first): qt = 15 - id/64, bh = id & 63.
// Block owns 128 q-rows; wave w owns 16-q groups {qb0+w*16, qb0+64+w*16}.
// S^T = mfma(K,Q): lane holds S[k=kb*16+lg*4+r][q=q0+l15] -> stats at l15=q.
// O^T = mfma(V^T,P): lane holds O[d=db*16+lg*4+r][q=q0+l15] -> rescale per-lane.
__global__ __launch_bounds__(256)
void attn_kernel(const u16* __restrict__ Q, const u16* __restrict__ K,
                 const u16* __restrict__ Vt, u16* __restrict__ AO) {
  __shared__ u16 sK[2][64 * 64];
  __shared__ u16 sV[2][64 * 64];
  __shared__ u16 sP[4][2][16 * 64];
  const int tid = threadIdx.x;
  const int lane = tid & 63, w = tid >> 6;
  const int l15 = lane & 15, lg = lane >> 4;
  const int id = blockIdx.x;
  const int qt = 15 - (id >> 6);
  const int bh = id & 63;
  const int qb0 = qt * 128;
  const size_t bh_off = (size_t)bh * TSEQ * DH;
  const int q0a = qb0 + w * 16;          // qg=0 16-q group
  const int q0b = qb0 + 64 + w * 16;     // qg=1 16-q group

  // Q B-fragments, loaded once (Q pre-scaled by 0.125*log2e in gemm1)
  short8 bq[2][2];
#pragma unroll
  for (int qg = 0; qg < 2; qg++) {
    int q0 = qg ? q0b : q0a;
#pragma unroll
    for (int kk = 0; kk < 2; kk++)
      bq[qg][kk] = *(const short8*)(Q + bh_off + (size_t)(q0 + l15) * DH + kk * 32 + lg * 8);
  }

  f32x4 accO[2][4] = {};                 // accO[qg][db]: O^T fragment
  float mrow[2] = {-3e38f, -3e38f};
  float lrow[2] = {0.f, 0.f};

  const int srow = tid >> 3, scb = tid & 7;

  auto stage = [&](int it, int buf) {
    const int k0 = it * 64;
    u16* dK = sK[buf];
    u16* dV = sV[buf];
#pragma unroll
    for (int i = 0; i < 2; i++) {
      int r = i * 32 + srow;
      int cb = scb ^ (r & 7);
      gload_lds16(K + bh_off + (size_t)(k0 + r) * DH + cb * 8, dK + i * 2048 + w * 512);
      gload_lds16(Vt + bh_off + (size_t)r * TSEQ + k0 + cb * 8, dV + i * 2048 + w * 512);
    }
  };

  const int ntiles = 2 * qt + 2;
  stage(0, 0);
  for (int it = 0; it < ntiles; ++it) {
    const int k0 = it * 64;
    __syncthreads();                       // stage(it) visible; prev-tile reads done
    const int cur = it & 1;
    if (it + 1 < ntiles) stage(it + 1, cur ^ 1);   // prefetch overlaps this tile
    if (k0 > q0b + 15) continue;           // wave fully done (causal); barriers still met

    const u16* cK = sK[cur];
    const u16* cV = sV[cur];

    // K A-fragments
    short8 ak[4][2];
#pragma unroll
    for (int kb = 0; kb < 4; kb++)
#pragma unroll
      for (int kk = 0; kk < 2; kk++) {
        int rk = kb * 16 + l15;
        ak[kb][kk] = *(const short8*)(cK + rk * 64 + (((kk * 4 + lg) ^ (rk & 7)) * 8));
      }

#pragma unroll
    for (int qg = 0; qg < 2; qg++) {
      const int q0 = qg ? q0b : q0a;
      if (k0 <= q0 + 15) {                 // this 16-q group active for this tile
        // S^T = K·Q : lane holds S[k = kb*16+lg*4+r][q = q0+l15]
        f32x4 accST[4] = {};
        __builtin_amdgcn_s_setprio(1);
#pragma unroll
        for (int kk = 0; kk < 2; kk++)
#pragma unroll
          for (int kb = 0; kb < 4; kb++)
            accST[kb] = MFMA16(ak[kb][kk], bq[qg][kk], accST[kb], 0, 0, 0);
        __builtin_amdgcn_s_setprio(0);

        if (k0 + 63 > q0) {                // causal mask needed on this tile
#pragma unroll
          for (int kb = 0; kb < 4; kb++)
#pragma unroll
            for (int r = 0; r < 4; r++)
              if (k0 + kb * 16 + lg * 4 + r > q0 + l15) accST[kb][r] = -1e30f;
        }

        // per-q tile max: 15 fmax (max3-fusable) + 2 shfl
        float t0 = fmaxf(fmaxf(accST[0][0], accST[0][1]), fmaxf(accST[0][2], accST[0][3]));
        float t1 = fmaxf(fmaxf(accST[1][0], accST[1][1]), fmaxf(accST[1][2], accST[1][3]));
        float t2 = fmaxf(fmaxf(accST[2][0], accST[2][1]), fmaxf(accST[2][2], accST[2][3]));
        float t3 = fmaxf(fmaxf(accST[3][0], accST[3][1]), fmaxf(accST[3][2], accST[3][3]));
        float mt = fmaxf(fmaxf(t0, t1), fmaxf(t2, t3));
        mt = fmaxf(mt, __shfl_xor(mt, 16));
        mt = fmaxf(mt, __shfl_xor(mt, 32));

        const float mold = mrow[qg];
        float mnew = mold;
        // T13 defer-max: skip rescale while max grows by <= 8 (P bounded by 2^8)
        if (!__all(mt <= mold + 8.0f)) {
          mnew = fmaxf(mold, mt);
          const float alpha = exp2v(mold - mnew);
          mrow[qg] = mnew;
          lrow[qg] *= alpha;
#pragma unroll
          for (int di = 0; di < 4; di++)
#pragma unroll
            for (int j = 0; j < 4; j++) accO[qg][di][j] *= alpha;
        }

        uint32_t* sPq = (uint32_t*)sP[w][qg];
        const int sw = l15 & 7;
        float rsum = 0.f;
#pragma unroll
        for (int kb = 0; kb < 4; kb++) {
          float p0 = exp2v(accST[kb][0] - mnew);
          float p1 = exp2v(accST[kb][1] - mnew);
          float p2 = exp2v(accST[kb][2] - mnew);
          float p3 = exp2v(accST[kb][3] - mnew);
          rsum += (p0 + p1) + (p2 + p3);
          // P[q=l15][k=kb*16+lg*4+{0..3}] -> one swizzled 8B write
          int off32 = l15 * 32 + ((((kb * 2 + (lg >> 1)) ^ sw) << 2) | ((lg & 1) << 1));
          uint32_t* dst = sPq + off32;
          dst[0] = cvtpk(p0, p1);
          dst[1] = cvtpk(p2, p3);
        }
        rsum += __shfl_xor(rsum, 16);
        rsum += __shfl_xor(rsum, 32);
        lrow[qg] += rsum;
      }
    }

    asm volatile("s_waitcnt lgkmcnt(0)" ::: "memory");   // P visible to own wave

    // V^T fragments (used as MFMA *A* operand: rows = d)
    short8 bv[2][4];
#pragma unroll
    for (int kk = 0; kk < 2; kk++)
#pragma unroll
      for (int di = 0; di < 4; di++) {
        int rv = di * 16 + l15;
        bv[kk][di] = *(const short8*)(cV + rv * 64 + (((kk * 4 + lg) ^ (rv & 7)) * 8));
      }
#pragma unroll
    for (int qg = 0; qg < 2; qg++) {
      const int q0 = qg ? q0b : q0a;
      if (k0 <= q0 + 15) {
        const u16* sPq = sP[w][qg];
        short8 ap[2];
#pragma unroll
        for (int kk = 0; kk < 2; kk++)
          ap[kk] = *(const short8*)(sPq + l15 * 64 + (((kk * 4 + lg) ^ (l15 & 7)) * 8));
        // O^T = V^T · P : D[d=db*16+lg*4+r][q=q0+l15]
        __builtin_amdgcn_s_setprio(1);
#pragma unroll
        for (int kk = 0; kk < 2; kk++)
#pragma unroll
          for (int db = 0; db < 4; db++)
            accO[qg][db] = MFMA16(bv[kk][db], ap[kk], accO[qg][db], 0, 0, 0);
        __builtin_amdgcn_s_setprio(0);
      }
    }
  }

  // epilogue: O^T frag -> lane writes q = q0+l15, d = db*16 + lg*4 + {0..3}
  const int b = bh >> 4, h = bh & 15;
#pragma unroll
  for (int qg = 0; qg < 2; qg++) {
    const int q0 = qg ? q0b : q0a;
    const int t = q0 + l15;
    const float inv = 1.0f / lrow[qg];
    u16* orow = AO + ((size_t)b * TSEQ + t) * N_EMBD + h * 64 + lg * 4;
#pragma unroll
    for (int db = 0; db < 4; db++) {
      u32x2 pkd;
      pkd[0] = cvtpk(accO[qg][db][0] * inv, accO[qg][db][1] * inv);
      pkd[1] = cvtpk(accO[qg][db][2] * inv, accO[qg][db][3] * inv);
      *(u32x2*)(orow + db * 16) = pkd;
    }
  }
}

extern "C" void kernel_launch(void* const* d_in, const int* in_sizes, int n_in,
                              void* d_out, int out_size, void* d_ws, size_t ws_size,
                              hipStream_t stream) {
  const float* x = (const float*)d_in[0];
  const float* w_qkv = (const float*)d_in[1];
  const float* w_out = (const float*)d_in[2];
  float* out = (float*)d_out;
  char* ws = (char*)d_ws;
  const size_t MB = 1 << 20;
  u16* xb    = (u16*)(ws);             // 16MB, reused as AO after gemm1
  u16* wqkvT = (u16*)(ws + 16 * MB);   // 6MB
  u16* woutT = (u16*)(ws + 22 * MB);   // 2MB
  u16* Qb    = (u16*)(ws + 24 * MB);   // 16MB
  u16* Kb    = (u16*)(ws + 40 * MB);   // 16MB
  u16* Vt    = (u16*)(ws + 56 * MB);   // 16MB (V^T written directly by gemm1)
  u16* AO    = xb;

  cvt_kernel<<<8192, 256, 0, stream>>>(x, xb, (BATCH * TSEQ * N_EMBD) / 4);
  transpose_bf16<<<dim3(32, 96, 1), 256, 0, stream>>>(w_qkv, wqkvT, 1024, 3072);
  transpose_bf16<<<dim3(32, 32, 1), 256, 0, stream>>>(w_out, woutT, 1024, 1024);
  gemm128<1><<<dim3(64, 24), 256, 0, stream>>>(xb, wqkvT, nullptr, Qb, Kb, Vt,
                                               BATCH * TSEQ, 3 * N_EMBD, N_EMBD);
  attn_kernel<<<1024, 256, 0, stream>>>(Qb, Kb, Vt, AO);
  gemm128<0><<<dim3(64, 8), 256, 0, stream>>>(AO, woutT, out, nullptr, nullptr, nullptr,
                                              BATCH * TSEQ, N_EMBD, N_EMBD);
}

// Round 6
// 225.746 us; speedup vs baseline: 2.5541x; 1.0553x over previous
//
#include <hip/hip_runtime.h>
#include <stdint.h>

typedef unsigned short u16;
typedef __attribute__((ext_vector_type(8))) short short8;    // 8 bf16 (4 VGPRs) MFMA frag
typedef __attribute__((ext_vector_type(4))) float f32x4;     // 16x16 MFMA C/D frag
typedef __attribute__((ext_vector_type(16))) float f32x16;   // 32x32 MFMA C/D frag
typedef __attribute__((ext_vector_type(4))) float float4v;
typedef __attribute__((ext_vector_type(2))) uint32_t u32x2;
typedef __attribute__((ext_vector_type(4))) uint32_t u32x4;

typedef const __attribute__((address_space(1))) void gvoid_t;
typedef __attribute__((address_space(3))) void lvoid_t;

#define N_EMBD 1024
#define NH 16
#define DH 64
#define TSEQ 2048
#define BATCH 4

#define MFMA16 __builtin_amdgcn_mfma_f32_16x16x32_bf16
#define MFMA32 __builtin_amdgcn_mfma_f32_32x32x16_bf16

__device__ __forceinline__ u16 f32_to_bf16(float f) {
  uint32_t x = __builtin_bit_cast(uint32_t, f);
  x = (x + 0x7FFFu + ((x >> 16) & 1u)) >> 16;   // round-to-nearest-even
  return (u16)x;
}

// HW packed f32x2 -> bf16x2 (RNE). No builtin on gfx950 -> inline asm (m240).
__device__ __forceinline__ uint32_t cvtpk(float lo, float hi) {
  uint32_t r;
  asm("v_cvt_pk_bf16_f32 %0, %1, %2" : "=v"(r) : "v"(lo), "v"(hi));
  return r;
}

__device__ __forceinline__ float exp2v(float x) { return __builtin_amdgcn_exp2f(x); }

__device__ __forceinline__ void gload_lds16(const void* g, void* l) {
  __builtin_amdgcn_global_load_lds((gvoid_t*)g, (lvoid_t*)l, 16, 0, 0);
}

// ---------------- elementwise f32 -> bf16 ----------------
__global__ void cvt_kernel(const float* __restrict__ in, u16* __restrict__ out, int n4) {
  int i = blockIdx.x * blockDim.x + threadIdx.x;
  if (i < n4) {
    float4v v = *(const float4v*)(in + (size_t)i * 4);
    u32x2 o;
    o[0] = cvtpk(v[0], v[1]);
    o[1] = cvtpk(v[2], v[3]);
    *(u32x2*)(out + (size_t)i * 4) = o;
  }
}

// ---------------- tiled transpose f32->bf16 (weights only) ----------------
__global__ void transpose_bf16(const float* __restrict__ in, u16* __restrict__ out,
                               int R, int C) {
  __shared__ u16 tile[32][33];
  int r0 = blockIdx.x * 32, c0 = blockIdx.y * 32;
  int tx = threadIdx.x & 31, ty = threadIdx.x >> 5;   // 256 thr: ty 0..7
#pragma unroll
  for (int i = 0; i < 4; i++)
    tile[ty + i * 8][tx] = f32_to_bf16(in[(size_t)(r0 + ty + i * 8) * C + c0 + tx]);
  __syncthreads();
#pragma unroll
  for (int i = 0; i < 4; i++)
    out[(size_t)(c0 + ty + i * 8) * R + r0 + tx] = tile[tx][ty + i * 8];
}

// ---------------- 128x128 GEMM, A[M][K] bf16, Bt[N][K] bf16 ----------------
// EPI==0: C f32 linear.
// EPI==1: scatter Q,K to [B,H,T,D] bf16 (Q pre-scaled); V direct to V^T [B,H,D,T].
template <int EPI>
__global__ __launch_bounds__(256)
void gemm128(const u16* __restrict__ A, const u16* __restrict__ Bt,
             float* __restrict__ Cf, u16* __restrict__ Qb, u16* __restrict__ Kb,
             u16* __restrict__ Vt, int M, int N, int K) {
  __shared__ u16 sA[128 * 64];
  __shared__ u16 sB[128 * 64];
  const int tid = threadIdx.x;
  const int lane = tid & 63, w = tid >> 6;
  const int wm = w >> 1, wn = w & 1;
  const int l15 = lane & 15, lg = lane >> 4;
  const int m0 = blockIdx.x * 128, n0 = blockIdx.y * 128;
  f32x4 acc[4][4] = {};
  const int srow = tid >> 3, scb = tid & 7;

  auto stage = [&](int k0) {
#pragma unroll
    for (int i = 0; i < 4; i++) {
      int row = i * 32 + srow;
      int cb = scb ^ (row & 7);                      // pre-swizzled SOURCE (rule #21)
      gload_lds16(A + (size_t)(m0 + row) * K + k0 + cb * 8, sA + i * 2048 + w * 512);
      gload_lds16(Bt + (size_t)(n0 + row) * K + k0 + cb * 8, sB + i * 2048 + w * 512);
    }
  };

  stage(0);
  for (int k0 = 0; k0 < K; k0 += 64) {
    __syncthreads();                                  // staging for k0 visible
    short8 af[4][2], bf[4][2];
#pragma unroll
    for (int mi = 0; mi < 4; mi++)
#pragma unroll
      for (int kk = 0; kk < 2; kk++) {
        int ra = wm * 64 + mi * 16 + l15;
        af[mi][kk] = *(const short8*)(sA + ra * 64 + ((kk * 4 + lg) ^ (ra & 7)) * 8);
        int rb = wn * 64 + mi * 16 + l15;
        bf[mi][kk] = *(const short8*)(sB + rb * 64 + ((kk * 4 + lg) ^ (rb & 7)) * 8);
      }
    if (k0 + 64 < K) {
      __syncthreads();                                // all frag reads done
      stage(k0 + 64);                                 // prefetch overlaps MFMA
    }
#pragma unroll
    for (int kk = 0; kk < 2; kk++)
#pragma unroll
      for (int mi = 0; mi < 4; mi++)
#pragma unroll
        for (int ni = 0; ni < 4; ni++)
          acc[mi][ni] = MFMA16(af[mi][kk], bf[ni][kk], acc[mi][ni], 0, 0, 0);
  }

#pragma unroll
  for (int mi = 0; mi < 4; mi++)
#pragma unroll
    for (int ni = 0; ni < 4; ni++) {
      const int mb = m0 + wm * 64 + mi * 16 + lg * 4;   // rows mb..mb+3 (t 4-aligned)
      const int n = n0 + wn * 64 + ni * 16 + l15;       // C col = lane&15
      if (EPI == 0) {
#pragma unroll
        for (int r = 0; r < 4; r++)
          Cf[(size_t)(mb + r) * N + n] = acc[mi][ni][r];
      } else {
        const int b = mb >> 11, t = mb & 2047;
        const int sec = n >> 10, c = n & 1023;          // sec uniform across wave
        const int h = c >> 6, d = c & 63;
        if (sec == 2) {
          // V^T [B,H,D,T]: 4 consecutive t per lane -> one 8B packed store
          u32x2 pkd;
          pkd[0] = cvtpk(acc[mi][ni][0], acc[mi][ni][1]);
          pkd[1] = cvtpk(acc[mi][ni][2], acc[mi][ni][3]);
          *(u32x2*)(Vt + ((size_t)(b * NH + h) * DH + d) * TSEQ + t) = pkd;
        } else {
          u16* dst = (sec == 0) ? Qb : Kb;
          const float sc = (sec == 0) ? 0.1803368801111204f : 1.0f;  // 1/8 * log2e
#pragma unroll
          for (int r = 0; r < 4; r++)
            dst[((size_t)(b * NH + h) * TSEQ + t + r) * DH + d] = f32_to_bf16(acc[mi][ni][r] * sc);
        }
      }
    }
}

// ---------------- causal flash attention, 32x32 MFMA, P fully in-register ----
// 1D grid of 1024 blocks (longest-first): qt = 15 - id/64, bh = id & 63.
// Block owns 128 q-rows; wave w owns 32 contiguous q at q0 = qb0 + w*32.
// S^T = mfma32(K,Q): lane(l31,b5) holds S[k=kb*32+(reg&3)+8*(reg>>2)+4*b5][q=q0+l31].
// P redistributed to B-frag via cvt_pk + shfl_xor(32) + cndmask (T12) - no LDS.
// O^T = mfma32(V^T,P): lane holds O[d=db*32+row(reg,b5)][q=q0+l31].
__global__ __launch_bounds__(256)
void attn_kernel(const u16* __restrict__ Q, const u16* __restrict__ K,
                 const u16* __restrict__ Vt, u16* __restrict__ AO) {
  __shared__ u16 sK[2][64 * 64];
  __shared__ u16 sV[2][64 * 64];
  const int tid = threadIdx.x;
  const int lane = tid & 63, w = tid >> 6;
  const int l31 = lane & 31;           // q index within wave tile
  const int b5 = lane >> 5;            // lane half
  const int id = blockIdx.x;
  const int qt = 15 - (id >> 6);
  const int bh = id & 63;
  const int qb0 = qt * 128;
  const size_t bh_off = (size_t)bh * TSEQ * DH;
  const int q0 = qb0 + w * 32;

  // Q B-frags (Q pre-scaled by 0.125*log2e): bq[ks] = Q[q0+l31][ks*16+b5*8 ..+7]
  short8 bq[4];
#pragma unroll
  for (int ks = 0; ks < 4; ks++)
    bq[ks] = *(const short8*)(Q + bh_off + (size_t)(q0 + l31) * DH + ks * 16 + b5 * 8);

  f32x16 accO[2] = {};                 // accO[db]: O^T fragment (d block db*32)
  float mrow = -3e38f, lrow = 0.f;

  const int srow = tid >> 3, scb = tid & 7;

  auto stage = [&](int it, int buf) {
    const int k0 = it * 64;
    u16* dK = sK[buf];
    u16* dV = sV[buf];
#pragma unroll
    for (int i = 0; i < 2; i++) {
      int r = i * 32 + srow;
      int cb = scb ^ (r & 7);
      gload_lds16(K + bh_off + (size_t)(k0 + r) * DH + cb * 8, dK + i * 2048 + w * 512);
      gload_lds16(Vt + bh_off + (size_t)r * TSEQ + k0 + cb * 8, dV + i * 2048 + w * 512);
    }
  };

  const int ntiles = 2 * qt + 2;
  stage(0, 0);
  for (int it = 0; it < ntiles; ++it) {
    const int k0 = it * 64;
    __syncthreads();                       // stage(it) visible; prev-tile reads done
    const int cur = it & 1;
    if (it + 1 < ntiles) stage(it + 1, cur ^ 1);   // prefetch overlaps this tile
    if (k0 > q0 + 31) continue;            // wave fully done (causal); barriers still met

    const u16* cK = sK[cur];
    const u16* cV = sV[cur];

    // K A-frags: ak[kb][ks]: K[kb*32+l31][ks*16 + b5*8 ..+7] (swizzled)
    short8 ak[2][4];
#pragma unroll
    for (int kb = 0; kb < 2; kb++)
#pragma unroll
      for (int ks = 0; ks < 4; ks++) {
        int rk = kb * 32 + l31;
        ak[kb][ks] = *(const short8*)(cK + rk * 64 + (((ks * 2 + b5) ^ (rk & 7)) * 8));
      }

    // S^T = K·Q
    f32x16 accS[2] = {};
    __builtin_amdgcn_s_setprio(1);
#pragma unroll
    for (int ks = 0; ks < 4; ks++)
#pragma unroll
      for (int kb = 0; kb < 2; kb++)
        accS[kb] = MFMA32(ak[kb][ks], bq[ks], accS[kb], 0, 0, 0);
    __builtin_amdgcn_s_setprio(0);

    // causal mask (single diagonal tile per wave)
    if (k0 + 63 > q0) {
#pragma unroll
      for (int kb = 0; kb < 2; kb++)
#pragma unroll
        for (int reg = 0; reg < 16; reg++) {
          int kg = k0 + kb * 32 + (reg & 3) + 8 * (reg >> 2) + 4 * b5;
          if (kg > q0 + l31) accS[kb][reg] = -1e30f;
        }
    }

    // per-q max: 31 fmax + 1 shfl (k spread over regs and b5 only)
    float mt = fmaxf(accS[0][0], accS[0][1]);
#pragma unroll
    for (int reg = 2; reg < 16; reg++) mt = fmaxf(mt, accS[0][reg]);
#pragma unroll
    for (int reg = 0; reg < 16; reg++) mt = fmaxf(mt, accS[1][reg]);
    mt = fmaxf(mt, __shfl_xor(mt, 32));

    float mnew = mrow;
    // T13 defer-max: skip rescale while max grows by <= 8 (P bounded by 2^8)
    if (!__all(mt <= mrow + 8.0f)) {
      mnew = fmaxf(mrow, mt);
      const float alpha = exp2v(mrow - mnew);
      mrow = mnew;
      lrow *= alpha;
#pragma unroll
      for (int db = 0; db < 2; db++)
#pragma unroll
        for (int reg = 0; reg < 16; reg++) accO[db][reg] *= alpha;
    }

    // exp2 + row-sum + pack to bf16 pairs: pk[kb][r1][d] = P(k=kb*32+8*r1+4*b5+2d+{0,1})
    uint32_t pk[2][4][2];
    float rsum = 0.f;
#pragma unroll
    for (int kb = 0; kb < 2; kb++)
#pragma unroll
      for (int r1 = 0; r1 < 4; r1++) {
        float p0 = exp2v(accS[kb][r1 * 4 + 0] - mnew);
        float p1 = exp2v(accS[kb][r1 * 4 + 1] - mnew);
        float p2 = exp2v(accS[kb][r1 * 4 + 2] - mnew);
        float p3 = exp2v(accS[kb][r1 * 4 + 3] - mnew);
        rsum += (p0 + p1) + (p2 + p3);
        pk[kb][r1][0] = cvtpk(p0, p1);
        pk[kb][r1][1] = cvtpk(p2, p3);
      }
    rsum += __shfl_xor(rsum, 32);
    lrow += rsum;

    // redistribute P to B-frag layout: bp[ks] slot s = pk[ks>>1][(ks&1)*2+b5_t][s&1]
    // pulled from lane half s>>1 (own or shfl_xor(32)); cndmask keeps reg idx static.
    short8 bp[4];
#pragma unroll
    for (int ks = 0; ks < 4; ks++) {
      const int kb = ks >> 1, base = (ks & 1) * 2;
      uint32_t A0 = b5 ? pk[kb][base + 1][0] : pk[kb][base][0];
      uint32_t A1 = b5 ? pk[kb][base + 1][1] : pk[kb][base][1];
      uint32_t B0 = b5 ? pk[kb][base][0] : pk[kb][base + 1][0];
      uint32_t B1 = b5 ? pk[kb][base][1] : pk[kb][base + 1][1];
      uint32_t Bs0 = __shfl_xor(B0, 32);
      uint32_t Bs1 = __shfl_xor(B1, 32);
      u32x4 v;
      v[0] = b5 ? Bs0 : A0;
      v[1] = b5 ? Bs1 : A1;
      v[2] = b5 ? A0 : Bs0;
      v[3] = b5 ? A1 : Bs1;
      bp[ks] = __builtin_bit_cast(short8, v);
    }

    // V^T A-frags + PV: O^T += V^T · P
    short8 av[2][4];
#pragma unroll
    for (int db = 0; db < 2; db++)
#pragma unroll
      for (int ks = 0; ks < 4; ks++) {
        int rv = db * 32 + l31;
        av[db][ks] = *(const short8*)(cV + rv * 64 + (((ks * 2 + b5) ^ (rv & 7)) * 8));
      }
    __builtin_amdgcn_s_setprio(1);
#pragma unroll
    for (int ks = 0; ks < 4; ks++)
#pragma unroll
      for (int db = 0; db < 2; db++)
        accO[db] = MFMA32(av[db][ks], bp[ks], accO[db], 0, 0, 0);
    __builtin_amdgcn_s_setprio(0);
  }

  // epilogue: lane writes q = q0+l31, d = db*32 + 8*r1 + 4*b5 + {0..3} (8B stores)
  const int b = bh >> 4, h = bh & 15;
  const int t = q0 + l31;
  const float inv = 1.0f / lrow;
  u16* orow = AO + ((size_t)b * TSEQ + t) * N_EMBD + h * 64 + 4 * b5;
#pragma unroll
  for (int db = 0; db < 2; db++)
#pragma unroll
    for (int r1 = 0; r1 < 4; r1++) {
      u32x2 pkd;
      pkd[0] = cvtpk(accO[db][r1 * 4 + 0] * inv, accO[db][r1 * 4 + 1] * inv);
      pkd[1] = cvtpk(accO[db][r1 * 4 + 2] * inv, accO[db][r1 * 4 + 3] * inv);
      *(u32x2*)(orow + db * 32 + r1 * 8) = pkd;
    }
}

extern "C" void kernel_launch(void* const* d_in, const int* in_sizes, int n_in,
                              void* d_out, int out_size, void* d_ws, size_t ws_size,
                              hipStream_t stream) {
  const float* x = (const float*)d_in[0];
  const float* w_qkv = (const float*)d_in[1];
  const float* w_out = (const float*)d_in[2];
  float* out = (float*)d_out;
  char* ws = (char*)d_ws;
  const size_t MB = 1 << 20;
  u16* xb    = (u16*)(ws);             // 16MB, reused as AO after gemm1
  u16* wqkvT = (u16*)(ws + 16 * MB);   // 6MB
  u16* woutT = (u16*)(ws + 22 * MB);   // 2MB
  u16* Qb    = (u16*)(ws + 24 * MB);   // 16MB
  u16* Kb    = (u16*)(ws + 40 * MB);   // 16MB
  u16* Vt    = (u16*)(ws + 56 * MB);   // 16MB (V^T written directly by gemm1)
  u16* AO    = xb;

  cvt_kernel<<<8192, 256, 0, stream>>>(x, xb, (BATCH * TSEQ * N_EMBD) / 4);
  transpose_bf16<<<dim3(32, 96, 1), 256, 0, stream>>>(w_qkv, wqkvT, 1024, 3072);
  transpose_bf16<<<dim3(32, 32, 1), 256, 0, stream>>>(w_out, woutT, 1024, 1024);
  gemm128<1><<<dim3(64, 24), 256, 0, stream>>>(xb, wqkvT, nullptr, Qb, Kb, Vt,
                                               BATCH * TSEQ, 3 * N_EMBD, N_EMBD);
  attn_kernel<<<1024, 256, 0, stream>>>(Qb, Kb, Vt, AO);
  gemm128<0><<<dim3(64, 8), 256, 0, stream>>>(AO, woutT, out, nullptr, nullptr, nullptr,
                                              BATCH * TSEQ, N_EMBD, N_EMBD);
}